// Round 2
// baseline (180.458 us; speedup 1.0000x reference)
//
#include <hip/hip_runtime.h>

// SmoothSkeletonDual: soft-morphology skeleton.
// dilate(x) = alpha*(logsumexp(patch/alpha) - log 9)   [softmax+entropy identity]
// erode(x)  = -dilate(-x)
// skel = sum_{k=0}^{10} clip(e_k - dilate(e_{k+1}), 0, 1),  e_k = erode^k(x)
//
// Fused per-iteration kernel: block computes E = erode(e_k) over a 64x32
// region (incl. 1-px halo) -> LDS, writes interior to global (e_{k+1}),
// then dilates from LDS and accumulates skel over the 62x30 interior.

#define HH 1024
#define WW 1024
#define NB 2
#define OXT 62   // output tile width
#define OYT 30   // output tile height
#define EXT 64   // E region width  (OXT+2)
#define EYT 32   // E region height (OYT+2)

// alpha = 0.05
constexpr float C1 = 28.85390081777927f;   // 1/(alpha*ln2)
constexpr float C2 = 0.03465735902799726f; // alpha*ln2
constexpr float C3 = 0.10986122886681098f; // alpha*ln(9)

__device__ __forceinline__ int mir(int i, int n) {
    return i < 0 ? -i : (i >= n ? 2 * n - 2 - i : i);
}

// erode value at in-range center (x,y); also returns center value.
__device__ __forceinline__ float erode_val(const float* __restrict__ p, int x, int y,
                                           float* xc) {
    int xm = mir(x - 1, WW), xp = mir(x + 1, WW);
    int ym = mir(y - 1, HH), yp = mir(y + 1, HH);
    const float* r0 = p + (size_t)ym * WW;
    const float* r1 = p + (size_t)y  * WW;
    const float* r2 = p + (size_t)yp * WW;
    float v[9] = {r0[xm], r0[x], r0[xp], r1[xm], r1[x], r1[xp], r2[xm], r2[x], r2[xp]};
    *xc = v[4];
    float mn = v[0];
    #pragma unroll
    for (int i = 1; i < 9; ++i) mn = fminf(mn, v[i]);
    float s = 0.f;
    #pragma unroll
    for (int i = 0; i < 9; ++i) s += __builtin_amdgcn_exp2f((mn - v[i]) * C1);
    return mn - C2 * __builtin_amdgcn_logf(s) + C3;
}

template <bool FIRST>
__global__ __launch_bounds__(256) void fused_k(const float* __restrict__ ein,
                                               float* __restrict__ eout,
                                               float* __restrict__ skel) {
    __shared__ float E[EYT][EXT];
    __shared__ float X[EYT][EXT];
    int tx = threadIdx.x, ty = threadIdx.y;   // 64 x 4
    int bx = blockIdx.x, by = blockIdx.y, b = blockIdx.z;
    const float* p = ein + (size_t)b * HH * WW;
    float* q = eout + (size_t)b * HH * WW;

    // Stage 1: E = erode(e_k) over EXT x EYT (4 rows per thread).
    int ex = bx * OXT - 1 + tx;      // global col of this E column (may be virtual)
    int mx = mir(ex, WW);
    #pragma unroll
    for (int r = 0; r < 8; ++r) {
        int j = r * 4 + ty;          // local E row 0..31
        int ey = by * OYT - 1 + j;   // global row (may be virtual)
        int my = mir(ey, HH);
        float xc;
        float e = erode_val(p, mx, my, &xc);
        E[j][tx] = e;
        X[j][tx] = xc;
        if (ex == mx && ey == my)    // in-range -> write e_{k+1}
            q[(size_t)ey * WW + ex] = e;
    }
    __syncthreads();

    // Stage 2: dilate(E) from LDS, skel (+)= clip(e_k - dilate, 0, 1).
    float* sk = skel + (size_t)b * HH * WW;
    int ox = bx * OXT + tx - 1;
    bool colok = (tx >= 1 && tx <= OXT && ox < WW);
    #pragma unroll
    for (int r = 0; r < 8; ++r) {
        int o = r * 4 + ty;          // output row in tile
        int oy = by * OYT + o;
        if (o < OYT && colok && oy < HH) {
            int j = o + 1;           // E row of the center
            float v[9] = {E[j-1][tx-1], E[j-1][tx], E[j-1][tx+1],
                          E[j  ][tx-1], E[j  ][tx], E[j  ][tx+1],
                          E[j+1][tx-1], E[j+1][tx], E[j+1][tx+1]};
            float mxv = v[0];
            #pragma unroll
            for (int i = 1; i < 9; ++i) mxv = fmaxf(mxv, v[i]);
            float s = 0.f;
            #pragma unroll
            for (int i = 0; i < 9; ++i) s += __builtin_amdgcn_exp2f((v[i] - mxv) * C1);
            float dil = mxv + C2 * __builtin_amdgcn_logf(s) - C3;
            float d = X[j][tx] - dil;
            d = fminf(fmaxf(d, 0.f), 1.f);
            size_t idx = (size_t)oy * WW + ox;
            if (FIRST) sk[idx] = d;
            else       sk[idx] = sk[idx] + d;
        }
    }
}

extern "C" void kernel_launch(void* const* d_in, const int* in_sizes, int n_in,
                              void* d_out, int out_size, void* d_ws, size_t ws_size,
                              hipStream_t stream) {
    const float* x0 = (const float*)d_in[0];
    float* skel = (float*)d_out;
    float* bufA = (float*)d_ws;                    // 8 MB
    float* bufB = bufA + (size_t)NB * HH * WW;     // 8 MB

    dim3 blk(64, 4, 1);
    dim3 grd((WW + OXT - 1) / OXT, (HH + OYT - 1) / OYT, NB);  // 17 x 35 x 2

    // k=0: e1 = erode(x0); skel = clip(x0 - dilate(e1))
    fused_k<true><<<grd, blk, 0, stream>>>(x0, bufA, skel);

    float* cur = bufA;   // e_k
    float* nxt = bufB;
    for (int k = 1; k <= 10; ++k) {
        fused_k<false><<<grd, blk, 0, stream>>>(cur, nxt, skel);
        float* t = cur; cur = nxt; nxt = t;
    }
}

// Round 3
// 118.998 us; speedup vs baseline: 1.5165x; 1.5165x over previous
//
#include <hip/hip_runtime.h>

// SmoothSkeletonDual, single-dispatch version.
// dilate(x) = alpha*(LSE(patch/alpha) - log 9); erode(x) = -dilate(-x)
// skel = sum_{k=0}^{10} clip(e_k - dilate(e_{k+1}), 0, 1), e_k = erode^k(x)
//
// Key fact: skel at pixel P needs e_0 only within a 12-pixel halo of P
// (e_{k+1} within 1, e_0 within k+2 <= 12). So one block loads a
// 128x66 tile (output 104x42 + halo 12, mirror-reflected at borders;
// reflection commutes with the symmetric LSE stencil) and runs all 11
// erode+dilate iterations in LDS ping-pong buffers. Zero grid syncs.

#define HH 1024
#define WW 1024
#define NB 2

#define TW 128            // tile width (input region)
#define TH 66             // tile height
#define HALO 12
#define OW (TW - 2*HALO)  // 104 output cols
#define OH (TH - 2*HALO)  // 42 output rows
#define NROW (OH/2)       // 21 output rows per thread (y-stride 2)
#define GX ((WW + OW - 1)/OW)  // 10
#define GY ((HH + OH - 1)/OH)  // 25

// alpha = 0.05
constexpr float C1 = 28.85390081777927f;   // 1/(alpha*ln2)
constexpr float C2 = 0.03465735902799726f; // alpha*ln2
constexpr float C3 = 0.10986122886681098f; // alpha*ln(9)

__device__ __forceinline__ int mir(int i, int n) {
    return i < 0 ? -i : (i >= n ? 2 * n - 2 - i : i);
}

__global__ __launch_bounds__(256, 2) void skel_k(const float* __restrict__ x0,
                                                 float* __restrict__ out) {
    __shared__ float A[TH][TW];
    __shared__ float B[TH][TW];
    int tid = threadIdx.x;
    int x  = tid & (TW - 1);   // 0..127
    int y0 = tid >> 7;         // 0..1; rows y0 + 2*i
    int bx = blockIdx.x, by = blockIdx.y, b = blockIdx.z;

    const float* src = x0 + (size_t)b * HH * WW;
    int gx0 = bx * OW - HALO;
    int gy0 = by * OH - HALO;

    // load e_0 tile (mirror-reflected)
    int mx = mir(gx0 + x, WW);
    #pragma unroll 4
    for (int i = 0; i < TH / 2; ++i) {
        int yy = y0 + 2 * i;
        int my = mir(gy0 + yy, HH);
        A[yy][x] = src[(size_t)my * WW + mx];
    }
    __syncthreads();

    float sk[NROW];
    #pragma unroll
    for (int i = 0; i < NROW; ++i) sk[i] = 0.f;

    float* cur = &A[0][0];   // holds e_{k-1}
    float* nxt = &B[0][0];

    for (int k = 1; k <= 11; ++k) {
        // erode cur -> nxt over x,yy in [k, T?-k)
        bool xin = (x >= k) & (x < TW - k);
        #pragma unroll 4
        for (int i = 0; i < (TH + 1) / 2; ++i) {
            int yy = y0 + 2 * i;
            if (xin && yy >= k && yy < TH - k) {
                const float* r0 = cur + (yy - 1) * TW + x;
                const float* r1 = cur + (yy    ) * TW + x;
                const float* r2 = cur + (yy + 1) * TW + x;
                float v0 = r0[-1], v1 = r0[0], v2 = r0[1];
                float v3 = r1[-1], v4 = r1[0], v5 = r1[1];
                float v6 = r2[-1], v7 = r2[0], v8 = r2[1];
                float mn = fminf(fminf(fminf(fminf(v0, v1), fminf(v2, v3)),
                                       fminf(fminf(v4, v5), fminf(v6, v7))), v8);
                float t = mn * C1;
                float s = __builtin_amdgcn_exp2f(fmaf(v0, -C1, t))
                        + __builtin_amdgcn_exp2f(fmaf(v1, -C1, t))
                        + __builtin_amdgcn_exp2f(fmaf(v2, -C1, t))
                        + __builtin_amdgcn_exp2f(fmaf(v3, -C1, t))
                        + __builtin_amdgcn_exp2f(fmaf(v4, -C1, t))
                        + __builtin_amdgcn_exp2f(fmaf(v5, -C1, t))
                        + __builtin_amdgcn_exp2f(fmaf(v6, -C1, t))
                        + __builtin_amdgcn_exp2f(fmaf(v7, -C1, t))
                        + __builtin_amdgcn_exp2f(fmaf(v8, -C1, t));
                nxt[yy * TW + x] = mn - C2 * __builtin_amdgcn_logf(s) + C3;
            }
        }
        __syncthreads();

        // dilate(nxt) on the output region; sk += clip(cur_center - dilate)
        bool xo = (x >= HALO) & (x < TW - HALO);
        if (xo) {
            #pragma unroll
            for (int i = 0; i < NROW; ++i) {
                int yy = HALO + y0 + 2 * i;
                const float* r0 = nxt + (yy - 1) * TW + x;
                const float* r1 = nxt + (yy    ) * TW + x;
                const float* r2 = nxt + (yy + 1) * TW + x;
                float v0 = r0[-1], v1 = r0[0], v2 = r0[1];
                float v3 = r1[-1], v4 = r1[0], v5 = r1[1];
                float v6 = r2[-1], v7 = r2[0], v8 = r2[1];
                float mxv = fmaxf(fmaxf(fmaxf(fmaxf(v0, v1), fmaxf(v2, v3)),
                                        fmaxf(fmaxf(v4, v5), fmaxf(v6, v7))), v8);
                float t = mxv * C1;
                float s = __builtin_amdgcn_exp2f(fmaf(v0, C1, -t))
                        + __builtin_amdgcn_exp2f(fmaf(v1, C1, -t))
                        + __builtin_amdgcn_exp2f(fmaf(v2, C1, -t))
                        + __builtin_amdgcn_exp2f(fmaf(v3, C1, -t))
                        + __builtin_amdgcn_exp2f(fmaf(v4, C1, -t))
                        + __builtin_amdgcn_exp2f(fmaf(v5, C1, -t))
                        + __builtin_amdgcn_exp2f(fmaf(v6, C1, -t))
                        + __builtin_amdgcn_exp2f(fmaf(v7, C1, -t))
                        + __builtin_amdgcn_exp2f(fmaf(v8, C1, -t));
                float dil = mxv + C2 * __builtin_amdgcn_logf(s) - C3;
                float d = cur[yy * TW + x] - dil;
                sk[i] += fminf(fmaxf(d, 0.f), 1.f);
            }
        }
        __syncthreads();

        float* t2 = cur; cur = nxt; nxt = t2;
    }

    // write out owned region
    int ox = gx0 + HALO + (x - HALO);           // = bx*OW + (x-HALO)
    if (x >= HALO && x < TW - HALO && ox < WW) {
        float* dst = out + (size_t)b * HH * WW;
        #pragma unroll
        for (int i = 0; i < NROW; ++i) {
            int oy = by * OH + y0 + 2 * i;
            if (oy < HH) dst[(size_t)oy * WW + ox] = sk[i];
        }
    }
}

extern "C" void kernel_launch(void* const* d_in, const int* in_sizes, int n_in,
                              void* d_out, int out_size, void* d_ws, size_t ws_size,
                              hipStream_t stream) {
    const float* x0 = (const float*)d_in[0];
    float* skel = (float*)d_out;
    dim3 blk(256, 1, 1);
    dim3 grd(GX, GY, NB);   // 10 x 25 x 2 = 500 blocks <= 512 co-resident
    skel_k<<<grd, blk, 0, stream>>>(x0, skel);
}

// Round 4
// 41.862 us; speedup vs baseline: 4.3108x; 2.8426x over previous
//
#include <hip/hip_runtime.h>

// SmoothSkeletonDual, single-dispatch, exponential-domain formulation.
// T'_0 = exp2(-x*C1); T'_{k+1} = box3x3(T'_k)   (unnormalized box filter!)
// term_k = clip(-C2*log2(T'_k(p) * sum_{q in 3x3} 1/T'_{k+1}(q)), 0, 1)
// skel = sum_{k=0}^{10} term_k
// (erode/dilate/entropy all collapse via exp2(-e_k*C1) = 9^{-k} T'_k and
//  C1*C2 = 1, C1*C3 = log2 9.)

#define HH 1024
#define WW 1024
#define NB 2
#define TW 128
#define TH 66
#define HALO 12
#define OW (TW - 2*HALO)   // 104
#define OH (TH - 2*HALO)   // 42
#define NROW (OH/2)        // 21 rows per thread-half
#define GX ((WW + OW - 1)/OW)   // 10
#define GY ((HH + OH - 1)/OH)   // 25

constexpr float C1 = 28.85390081777927f;   // 1/(alpha*ln2)
constexpr float C2 = 0.03465735902799726f; // alpha*ln2

__device__ __forceinline__ int mir(int i, int n) {
    return i < 0 ? -i : (i >= n ? 2 * n - 2 - i : i);
}

__device__ __forceinline__ float rcp3(const float (&T)[TH][TW], int y, int x) {
    return __builtin_amdgcn_rcpf(T[y][x - 1]) +
           __builtin_amdgcn_rcpf(T[y][x]) +
           __builtin_amdgcn_rcpf(T[y][x + 1]);
}

// D = box3x3(S) on rows [k, TH-k), cols [k, TW-k); separable, register-rolled.
__device__ __forceinline__ void boxpass(const float (&S)[TH][TW], float (&D)[TH][TW],
                                        int k, int x, int y0) {
    if (x < k || x >= TW - k) return;
    int ys = y0 ? (TH / 2) : k;
    int ye = y0 ? (TH - k) : (TH / 2);
    float h0 = S[ys - 1][x - 1] + S[ys - 1][x] + S[ys - 1][x + 1];
    float h1 = S[ys][x - 1] + S[ys][x] + S[ys][x + 1];
    for (int y = ys; y < ye; ++y) {
        float h2 = S[y + 1][x - 1] + S[y + 1][x] + S[y + 1][x + 1];
        D[y][x] = h0 + h1 + h2;
        h0 = h1; h1 = h2;
    }
}

// sk += clip(-C2*log2(P[y][x] * box3x3(1/T)[y][x]), 0, 1) on output region.
__device__ __forceinline__ void termpass(const float (&P)[TH][TW], const float (&T)[TH][TW],
                                         float (&sk)[NROW], int x, int y0) {
    if (x < HALO || x >= TW - HALO) return;
    int ys = HALO + y0 * NROW;   // 12 or 33
    float hr0 = rcp3(T, ys - 1, x);
    float hr1 = rcp3(T, ys, x);
    #pragma unroll
    for (int i = 0; i < NROW; ++i) {
        int y = ys + i;
        float hr2 = rcp3(T, y + 1, x);
        float s = hr0 + hr1 + hr2;
        float t = -C2 * __builtin_amdgcn_logf(P[y][x] * s);
        sk[i] += fminf(fmaxf(t, 0.f), 1.f);
        hr0 = hr1; hr1 = hr2;
    }
}

__global__ __launch_bounds__(256, 2) void skel_k(const float* __restrict__ x0,
                                                 float* __restrict__ out) {
    __shared__ float A[TH][TW];
    __shared__ float B[TH][TW];
    int tid = threadIdx.x;
    int x  = tid & (TW - 1);   // column owned by this thread
    int y0 = tid >> 7;         // 0 = top half rows, 1 = bottom half
    int bx = blockIdx.x, by = blockIdx.y, b = blockIdx.z;
    int gx0 = bx * OW - HALO, gy0 = by * OH - HALO;

    // init: T'_0 = exp2(-x * C1), mirror-loaded (row-mode, coalesced)
    const float* src = x0 + (size_t)b * HH * WW;
    int mx = mir(gx0 + x, WW);
    #pragma unroll 3
    for (int i = 0; i < TH / 2; ++i) {
        int yy = y0 + 2 * i;
        int my = mir(gy0 + yy, HH);
        A[yy][x] = __builtin_amdgcn_exp2f(src[(size_t)my * WW + mx] * (-C1));
    }
    __syncthreads();

    float sk[NROW];
    #pragma unroll
    for (int i = 0; i < NROW; ++i) sk[i] = 0.f;

    #pragma unroll 1
    for (int kk = 0; kk < 6; ++kk) {
        int k = 2 * kk + 1;
        boxpass(A, B, k, x, y0);      // T'_k  (k odd) -> B
        __syncthreads();
        termpass(A, B, sk, x, y0);    // term_{k-1}
        __syncthreads();
        if (kk == 5) break;           // k = 11 done
        boxpass(B, A, k + 1, x, y0);  // T'_{k+1} -> A
        __syncthreads();
        termpass(B, A, sk, x, y0);    // term_k
        __syncthreads();
    }

    // write owned columns (one full row per step across lanes -> coalesced)
    int ox = bx * OW + (x - HALO);
    if (x >= HALO && x < TW - HALO && ox < WW) {
        float* dst = out + (size_t)b * HH * WW;
        #pragma unroll
        for (int i = 0; i < NROW; ++i) {
            int oy = by * OH + y0 * NROW + i;
            if (oy < HH) dst[(size_t)oy * WW + ox] = sk[i];
        }
    }
}

extern "C" void kernel_launch(void* const* d_in, const int* in_sizes, int n_in,
                              void* d_out, int out_size, void* d_ws, size_t ws_size,
                              hipStream_t stream) {
    const float* x0 = (const float*)d_in[0];
    float* skel = (float*)d_out;
    dim3 blk(256, 1, 1);
    dim3 grd(GX, GY, NB);   // 10 x 25 x 2 = 500 blocks, 2/CU co-resident
    skel_k<<<grd, blk, 0, stream>>>(x0, skel);
}

// Round 6
// 38.677 us; speedup vs baseline: 4.6658x; 1.0823x over previous
//
#include <hip/hip_runtime.h>

// SmoothSkeletonDual, single-dispatch, exp-domain + DPP neighbor exchange.
// T'_0 = exp2(-x*C1); T'_{k+1} = box3x3(T'_k) (unnormalized).
// term_k = clip(-C2*log2(T'_k(p) * sum_{3x3} 1/T'_{k+1}(q)), 0, 1)
// skel = sum_{k=0}^{10} term_k
//
// Tile 256x66 (output 232x42, halo 12). 512 threads = 8 waves; each lane
// owns 4 adjacent columns (ds_read_b128/ds_write_b128); cross-lane
// neighbor columns come from DPP wave shifts (VALU-rate, zero LDS traffic).
// NOTE DPP direction: WF_SHR1 (0x138) -> lane i reads lane i-1;
//                     WF_SHL1 (0x130) -> lane i reads lane i+1.

#define HH 1024
#define WW 1024
#define NB 2
#define TW 256
#define TH 66
#define HALO 12
#define OW (TW - 2*HALO)   // 232
#define OH (TH - 2*HALO)   // 42
#define GX 5               // ceil(1024/232)
#define GY 25              // ceil(1024/42)
#define NTR 6              // max term rows per wave

constexpr float C1 = 28.85390081777927f;   // 1/(alpha*ln2)
constexpr float C2 = 0.03465735902799726f; // alpha*ln2

__device__ __forceinline__ int mir(int i, int n) {
    return i < 0 ? -i : (i >= n ? 2 * n - 2 - i : i);
}

// lane i <- lane i-1 (WF_SHR1; lane 0 gets 0 -- only feeds never-valid cols)
__device__ __forceinline__ float nbrL(float v) {
    return __int_as_float(__builtin_amdgcn_update_dpp(
        0, __float_as_int(v), 0x138, 0xf, 0xf, true));
}
// lane i <- lane i+1 (WF_SHL1; lane 63 gets 0)
__device__ __forceinline__ float nbrR(float v) {
    return __int_as_float(__builtin_amdgcn_update_dpp(
        0, __float_as_int(v), 0x130, 0xf, 0xf, true));
}

struct F4 { float a, b, c, d; };

// 3-tap horizontal sums for this lane's 4 columns of one row.
__device__ __forceinline__ F4 colsum(const float* row, int lane) {
    float4 t = *reinterpret_cast<const float4*>(row + 4 * lane);
    float tm = nbrL(t.w), tp = nbrR(t.x);
    F4 r;
    r.a = tm  + t.x + t.y;
    r.b = t.x + t.y + t.z;
    r.c = t.y + t.z + t.w;
    r.d = t.z + t.w + tp;
    return r;
}

// 3-tap horizontal sums of reciprocals.
__device__ __forceinline__ F4 rcpsum(const float* row, int lane) {
    float4 t = *reinterpret_cast<const float4*>(row + 4 * lane);
    float r0 = __builtin_amdgcn_rcpf(t.x);
    float r1 = __builtin_amdgcn_rcpf(t.y);
    float r2 = __builtin_amdgcn_rcpf(t.z);
    float r3 = __builtin_amdgcn_rcpf(t.w);
    float rm = nbrL(r3), rp = nbrR(r0);
    F4 r;
    r.a = rm + r0 + r1;
    r.b = r0 + r1 + r2;
    r.c = r1 + r2 + r3;
    r.d = r2 + r3 + rp;
    return r;
}

__device__ __forceinline__ float clamp01(float v) {
    return fminf(fmaxf(v, 0.f), 1.f);
}

__global__ __launch_bounds__(512, 1) void skel_k(const float* __restrict__ x0,
                                                 float* __restrict__ out) {
    __shared__ float A[TH * TW];
    __shared__ float B[TH * TW];
    const int tid  = threadIdx.x;
    const int lane = tid & 63;
    const int w    = tid >> 6;       // wave 0..7
    const int bx = blockIdx.x, by = blockIdx.y, b = blockIdx.z;
    const int gx0 = bx * OW - HALO, gy0 = by * OH - HALO;
    const float* src = x0 + (size_t)b * HH * WW;

    // ---- load T'_0 = exp2(-x*C1)
    bool interior = (gx0 >= 0) && (gx0 + TW <= WW) && (gy0 >= 0) && (gy0 + TH <= HH);
    if (interior) {
        for (int y = w; y < TH; y += 8) {
            float4 t = *reinterpret_cast<const float4*>(
                src + (size_t)(gy0 + y) * WW + gx0 + 4 * lane);
            float4 e;
            e.x = __builtin_amdgcn_exp2f(t.x * -C1);
            e.y = __builtin_amdgcn_exp2f(t.y * -C1);
            e.z = __builtin_amdgcn_exp2f(t.z * -C1);
            e.w = __builtin_amdgcn_exp2f(t.w * -C1);
            *reinterpret_cast<float4*>(&A[y * TW + 4 * lane]) = e;
        }
    } else {
        for (int y = w; y < TH; y += 8) {
            int my = mir(gy0 + y, HH);
            const float* r = src + (size_t)my * WW;
            float4 e;
            e.x = __builtin_amdgcn_exp2f(r[mir(gx0 + 4 * lane + 0, WW)] * -C1);
            e.y = __builtin_amdgcn_exp2f(r[mir(gx0 + 4 * lane + 1, WW)] * -C1);
            e.z = __builtin_amdgcn_exp2f(r[mir(gx0 + 4 * lane + 2, WW)] * -C1);
            e.w = __builtin_amdgcn_exp2f(r[mir(gx0 + 4 * lane + 3, WW)] * -C1);
            *reinterpret_cast<float4*>(&A[y * TW + 4 * lane]) = e;
        }
    }
    __syncthreads();

    float sk[NTR][4];
    #pragma unroll
    for (int i = 0; i < NTR; ++i)
        sk[i][0] = sk[i][1] = sk[i][2] = sk[i][3] = 0.f;

    // fixed term strip per wave: rows [trs, tre) of [12,54)
    const int trs = HALO + (21 * w) / 4;
    const int tre = HALO + (21 * (w + 1)) / 4;

    float* S = A;
    float* D = B;
    #pragma unroll 1
    for (int j = 0; j <= 10; ++j) {
        // ---- box pass: D = box3x3(S) on rows [j+1, 65-j)
        {
            const int n  = TH - 2 - 2 * j;           // 64-2j rows
            const int rs = j + 1 + ((n * w) >> 3);
            const int re = j + 1 + ((n * (w + 1)) >> 3);
            F4 p = colsum(&S[(rs - 1) * TW], lane);
            F4 c = colsum(&S[rs * TW], lane);
            #pragma unroll 3
            for (int y = rs; y < re; ++y) {
                F4 nx = colsum(&S[(y + 1) * TW], lane);
                float4 o;
                o.x = p.a + c.a + nx.a;
                o.y = p.b + c.b + nx.b;
                o.z = p.c + c.c + nx.c;
                o.w = p.d + c.d + nx.d;
                *reinterpret_cast<float4*>(&D[y * TW + 4 * lane]) = o;
                p = c; c = nx;
            }
        }
        __syncthreads();
        // ---- term pass j: sk += clip(-C2*log2(S_center * rcpbox3x3(D)))
        {
            F4 p = rcpsum(&D[(trs - 1) * TW], lane);
            F4 c = rcpsum(&D[trs * TW], lane);
            #pragma unroll
            for (int i = 0; i < NTR; ++i) {
                int y = trs + i;
                if (y < tre) {
                    F4 nx = rcpsum(&D[(y + 1) * TW], lane);
                    float4 P = *reinterpret_cast<const float4*>(&S[y * TW + 4 * lane]);
                    sk[i][0] += clamp01(-C2 * __builtin_amdgcn_logf(P.x * (p.a + c.a + nx.a)));
                    sk[i][1] += clamp01(-C2 * __builtin_amdgcn_logf(P.y * (p.b + c.b + nx.b)));
                    sk[i][2] += clamp01(-C2 * __builtin_amdgcn_logf(P.z * (p.c + c.c + nx.c)));
                    sk[i][3] += clamp01(-C2 * __builtin_amdgcn_logf(P.w * (p.d + c.d + nx.d)));
                    p = c; c = nx;
                }
            }
        }
        __syncthreads();
        float* t = S; S = D; D = t;
    }

    // ---- write skel (lanes 3..60 hold the 232 output cols; 4-aligned)
    if (lane >= 3 && lane <= 60) {
        int ox = gx0 + 4 * lane;          // = bx*232 + (4*lane - 12)
        if (ox + 3 < WW) {
            float* dst = out + (size_t)b * HH * WW;
            #pragma unroll
            for (int i = 0; i < NTR; ++i) {
                int y = trs + i;
                int oy = gy0 + y;
                if (y < tre && oy < HH) {
                    float4 o;
                    o.x = sk[i][0]; o.y = sk[i][1]; o.z = sk[i][2]; o.w = sk[i][3];
                    *reinterpret_cast<float4*>(&dst[(size_t)oy * WW + ox]) = o;
                }
            }
        }
    }
}

extern "C" void kernel_launch(void* const* d_in, const int* in_sizes, int n_in,
                              void* d_out, int out_size, void* d_ws, size_t ws_size,
                              hipStream_t stream) {
    const float* x0 = (const float*)d_in[0];
    float* skel = (float*)d_out;
    dim3 blk(512, 1, 1);
    dim3 grd(GX, GY, NB);   // 5 x 25 x 2 = 250 blocks, 1/CU, single round
    skel_k<<<grd, blk, 0, stream>>>(x0, skel);
}